// Round 1
// baseline (356.302 us; speedup 1.0000x reference)
//
#include <hip/hip_runtime.h>
#include <hip/hip_cooperative_groups.h>
#include <float.h>
#include <math.h>

// Problem constants (S=4096 tokens, E=64 experts, CAP=128)
#define SS 4096
#define EE 64
#define CAPC 128
#define ROW 8192                  // E*CAP floats per token per tensor
#define SEC (4096LL * 64 * 128)   // elements per [S,E,C] tensor
#define NGATE 256                 // gate blocks (16 tokens each)
#define TPB_TOK 16                // tokens per gate block
#define NBLK 512                  // total cooperative blocks (2/CU guaranteed)
// Zero-fill split: 2*SEC floats = 16,777,216 float4.
// Gate blocks fill less so their ~5us of gate VALU work hides under the
// fill-only blocks' larger share.  256*28672 + 256*36864 = 16,777,216.
#define F4G 28672                 // float4 per gate block  (112 per thread)
#define F4F 36864                 // float4 per fill block  (144 per thread)

namespace cg = cooperative_groups;

// ---------------------------------------------------------------------------
// Fused single cooperative kernel:
//   phase A (blocks 0..255): gate for 16 tokens (4 waves x 4 tokens),
//       publish per-block counts/gate-sums to ws; token meta stays in LDS.
//   phase B (all 512 blocks): zero-fill a contiguous slice of out.
//   grid.sync()
//   phase C (blocks 0..255): redundant per-block prefix scan of the
//       L2-resident count arrays + scatter of own 16 tokens; block 0 l_aux.
// Identical arithmetic & reduction order to the previous 2-kernel version
// (bitwise-same outputs); removes K2 dispatch + launch gap + meta round-trip.
// ---------------------------------------------------------------------------
__global__ __launch_bounds__(256, 2) void k_fused(
    const float* __restrict__ logits,
    const float* __restrict__ noise,
    int*   __restrict__ bc1,      // [256][64] per-block top1 counts
    int*   __restrict__ bc2,      // [256][64] per-block top2 counts
    float* __restrict__ pg,       // [256][64] per-block gate sums
    float* __restrict__ out)
{
    const int tid = threadIdx.x;
    const int b   = blockIdx.x;

    __shared__ int    s_idx1[TPB_TOK], s_idx2[TPB_TOK];
    __shared__ float  s_gate[TPB_TOK][64];
    __shared__ int    s_meta[TPB_TOK];     // packed idx/ranks (was tokmeta)
    __shared__ float2 s_g[TPB_TOK];        // raw g1,g2        (was tokg)
    __shared__ int    s_off1[64], s_off2[64], s_cnt1[64];
    __shared__ float  s_gs[64];

    // ---- phase A: gate (blocks 0..255 only) ----
    if (b < NGATE) {
        const int wave = tid >> 6;
        const int lane = tid & 63;

        #pragma unroll
        for (int t4 = 0; t4 < 4; ++t4) {
            const int t = wave * 4 + t4;        // token within block
            const int s = b * TPB_TOK + t;
            const float l = logits[s * EE + lane];
            const float n = noise [s * EE + lane];

            // argmax over logits, first-index tie-break (all lanes agree)
            float v = l; int bi = lane;
            #pragma unroll
            for (int off = 32; off; off >>= 1) {
                float v2 = __shfl_xor(v, off, 64);
                int   i2 = __shfl_xor(bi, off, 64);
                if (v2 > v || (v2 == v && i2 < bi)) { v = v2; bi = i2; }
            }
            const int idx1 = bi;

            float e = expf(l - v);
            float sum = e;
            #pragma unroll
            for (int off = 32; off; off >>= 1) sum += __shfl_xor(sum, off, 64);
            const float gate = e / sum;

            // top-2 from logits+noise with top-1 masked to -FLT_MAX
            float lw = (lane == idx1) ? -FLT_MAX : (l + n);
            float v2v = lw; int bi2 = lane;
            #pragma unroll
            for (int off = 32; off; off >>= 1) {
                float q  = __shfl_xor(v2v, off, 64);
                int   i2 = __shfl_xor(bi2, off, 64);
                if (q > v2v || (q == v2v && i2 < bi2)) { v2v = q; bi2 = i2; }
            }
            const int idx2 = bi2;

            s_gate[t][lane] = gate;
            const float g1v = __shfl(gate, idx1, 64);
            const float g2v = __shfl(gate, idx2, 64);
            if (lane == 0) {
                s_idx1[t] = idx1;
                s_idx2[t] = idx2;
                s_g[t] = make_float2(g1v, g2v);
            }
        }
        __syncthreads();

        // per-block expert counts + gate sums, local ranks
        if (tid < 64) {
            int c1 = 0, c2 = 0;
            float gs = 0.f;
            #pragma unroll
            for (int j = 0; j < TPB_TOK; ++j) {
                c1 += (s_idx1[j] == tid);
                c2 += (s_idx2[j] == tid);
                gs += s_gate[j][tid];
            }
            bc1[b * 64 + tid] = c1;
            bc2[b * 64 + tid] = c2;
            pg [b * 64 + tid] = gs;
        } else if (tid < 64 + TPB_TOK) {
            const int t = tid - 64;
            const int m1 = s_idx1[t], m2 = s_idx2[t];
            int r1 = 0, r2 = 0;
            for (int j = 0; j < t; ++j) {
                r1 += (s_idx1[j] == m1);
                r2 += (s_idx2[j] == m2);
            }
            s_meta[t] = m1 | (m2 << 6) | (r1 << 12) | (r2 << 17);
        }
    }

    // ---- phase B: zero-fill share (all blocks) ----
    {
        const float4 z = make_float4(0.f, 0.f, 0.f, 0.f);
        if (b < NGATE) {
            float4* p = (float4*)out + (long)b * F4G;
            #pragma unroll 8
            for (int i = 0; i < F4G / 256; ++i) p[i * 256 + tid] = z;
        } else {
            float4* p = (float4*)out + (long)NGATE * F4G + (long)(b - NGATE) * F4F;
            #pragma unroll 8
            for (int i = 0; i < F4F / 256; ++i) p[i * 256 + tid] = z;
            if (b == NBLK - 1 && tid == 0) out[2 * SEC] = 0.f;  // last element
        }
    }

    // ---- grid-wide barrier: counts visible, zeros landed ----
    cg::this_grid().sync();
    if (b >= NGATE) return;

    // ---- phase C: redundant prefix scan (bc arrays L2-resident) + scatter ----
    if (tid < 64) {
        int o1 = 0, mine = 0;
        #pragma unroll 8
        for (int blk = 0; blk < NGATE; ++blk) {
            if (blk == b) mine = o1;
            o1 += bc1[blk * 64 + tid];
        }
        s_off1[tid] = mine;
        s_cnt1[tid] = o1;
    } else if (tid < 128) {
        const int e = tid - 64;
        int o2 = 0, mine = 0;
        #pragma unroll 8
        for (int blk = 0; blk < NGATE; ++blk) {
            if (blk == b) mine = o2;
            o2 += bc2[blk * 64 + e];
        }
        s_off2[e] = mine;
    } else if (tid < 192 && b == 0) {
        const int e = tid - 128;
        float gs = 0.f;
        #pragma unroll 8
        for (int blk = 0; blk < NGATE; ++blk) gs += pg[blk * 64 + e];
        s_gs[e] = gs;
    }
    __syncthreads();

    if (tid < TPB_TOK) {
        const int s = b * TPB_TOK + tid;
        const int m = s_meta[tid];
        const int i1  =  m        & 63;
        const int i2  = (m >> 6)  & 63;
        const int lr1 = (m >> 12) & 31;
        const int lr2 = (m >> 17) & 31;
        const float2 g = s_g[tid];
        const int loc1 = lr1 + s_off1[i1];
        const int loc2 = lr2 + s_off2[i2] + s_cnt1[i2];
        float g1 = g.x, g2 = g.y;
        const bool k1 = loc1 < CAPC, k2 = loc2 < CAPC;
        g1 = k1 ? g1 : 0.f;
        g2 = k2 ? g2 : 0.f;
        const float denom = fmaxf(g1 + g2, 1.1920929e-07f);  // finfo(f32).eps
        g1 /= denom;
        g2 /= denom;
        float* combine = out + 1;
        float* mask    = out + 1 + SEC;
        const long base = (long)s * ROW;
        if (k1 && g1 != 0.f) {
            const long p = base + (long)i1 * CAPC + loc1;
            combine[p] = g1;
            mask[p]    = 1.f;
        }
        if (k2 && g2 != 0.f) {
            const long p = base + (long)i2 * CAPC + loc2;
            combine[p] = g2;
            mask[p]    = 1.f;
        }
    } else if (tid == 64 + TPB_TOK && b == 0) {
        // l_aux = (E / S^2) * sum_e gs_e * cnt1_e
        float prod = 0.f;
        #pragma unroll 8
        for (int e = 0; e < 64; ++e) prod += s_gs[e] * (float)s_cnt1[e];
        out[0] = prod * (float)EE / ((float)SS * (float)SS);
    }
}

// ---------------------------------------------------------------------------
// Launch: one cooperative kernel (grid.sync replaces the K1->K2 boundary).
// ---------------------------------------------------------------------------
extern "C" void kernel_launch(void* const* d_in, const int* in_sizes, int n_in,
                              void* d_out, int out_size, void* d_ws, size_t ws_size,
                              hipStream_t stream) {
    const float* logits = (const float*)d_in[0];
    const float* noise  = (const float*)d_in[1];
    float* out = (float*)d_out;

    char* ws = (char*)d_ws;
    int*   bc1 = (int*)  (ws + 0);        // 64 KB
    int*   bc2 = (int*)  (ws + 65536);    // 64 KB
    float* pg  = (float*)(ws + 131072);   // 64 KB

    void* args[] = { (void*)&logits, (void*)&noise, (void*)&bc1,
                     (void*)&bc2, (void*)&pg, (void*)&out };
    hipLaunchCooperativeKernel((void*)k_fused, dim3(NBLK), dim3(256),
                               args, 0, stream);
}

// Round 2
// 284.520 us; speedup vs baseline: 1.2523x; 1.2523x over previous
//
#include <hip/hip_runtime.h>
#include <float.h>
#include <math.h>

// Problem constants (S=4096 tokens, E=64 experts, CAP=128)
#define SS 4096
#define EE 64
#define CAPC 128
#define ROW 8192                  // E*CAP floats per token per tensor
#define SEC (4096LL * 64 * 128)   // elements per [S,E,C] tensor
#define NGATE 256                 // gate blocks (16 tokens each)
#define TPB_TOK 16                // tokens per gate block
#define NW 1024                   // writer blocks
#define TPW 4                     // tokens per writer block

// ---------------------------------------------------------------------------
// K1: gate only (round-0 gate math, fill stripped).  256 blocks x 256 thr,
// 4 waves x 4 tokens.  Writes per-block counts/gate-sums + token meta/gates.
// ---------------------------------------------------------------------------
__global__ __launch_bounds__(256) void k1_gate(
    const float* __restrict__ logits,
    const float* __restrict__ noise,
    int*   __restrict__ bc1,      // [256][64] per-block top1 counts
    int*   __restrict__ bc2,      // [256][64] per-block top2 counts
    float* __restrict__ pg,       // [256][64] per-block gate sums
    int*   __restrict__ tokmeta,  // [4096] packed idx/ranks
    float2* __restrict__ tokg)    // [4096] raw g1,g2
{
    const int tid  = threadIdx.x;
    const int b    = blockIdx.x;
    const int wave = tid >> 6;
    const int lane = tid & 63;

    __shared__ int   s_idx1[TPB_TOK], s_idx2[TPB_TOK];
    __shared__ float s_gate[TPB_TOK][64];

    #pragma unroll
    for (int t4 = 0; t4 < 4; ++t4) {
        const int t = wave * 4 + t4;        // token within block
        const int s = b * TPB_TOK + t;
        const float l = logits[s * EE + lane];
        const float n = noise [s * EE + lane];

        // argmax over logits, first-index tie-break (all lanes agree)
        float v = l; int bi = lane;
        #pragma unroll
        for (int off = 32; off; off >>= 1) {
            float v2 = __shfl_xor(v, off, 64);
            int   i2 = __shfl_xor(bi, off, 64);
            if (v2 > v || (v2 == v && i2 < bi)) { v = v2; bi = i2; }
        }
        const int idx1 = bi;

        float e = expf(l - v);
        float sum = e;
        #pragma unroll
        for (int off = 32; off; off >>= 1) sum += __shfl_xor(sum, off, 64);
        const float gate = e / sum;

        // top-2 from logits+noise with top-1 masked to -FLT_MAX
        float lw = (lane == idx1) ? -FLT_MAX : (l + n);
        float v2v = lw; int bi2 = lane;
        #pragma unroll
        for (int off = 32; off; off >>= 1) {
            float q  = __shfl_xor(v2v, off, 64);
            int   i2 = __shfl_xor(bi2, off, 64);
            if (q > v2v || (q == v2v && i2 < bi2)) { v2v = q; bi2 = i2; }
        }
        const int idx2 = bi2;

        s_gate[t][lane] = gate;
        const float g1v = __shfl(gate, idx1, 64);
        const float g2v = __shfl(gate, idx2, 64);
        if (lane == 0) {
            s_idx1[t] = idx1;
            s_idx2[t] = idx2;
            tokg[s] = make_float2(g1v, g2v);
        }
    }
    __syncthreads();

    // per-block expert counts + gate sums, local ranks
    if (tid < 64) {
        int c1 = 0, c2 = 0;
        float gs = 0.f;
        #pragma unroll
        for (int j = 0; j < TPB_TOK; ++j) {
            c1 += (s_idx1[j] == tid);
            c2 += (s_idx2[j] == tid);
            gs += s_gate[j][tid];
        }
        bc1[b * 64 + tid] = c1;
        bc2[b * 64 + tid] = c2;
        pg [b * 64 + tid] = gs;
    } else if (tid < 64 + TPB_TOK) {
        const int t = tid - 64;
        const int m1 = s_idx1[t], m2 = s_idx2[t];
        int r1 = 0, r2 = 0;
        for (int j = 0; j < t; ++j) {
            r1 += (s_idx1[j] == m1);
            r2 += (s_idx2[j] == m2);
        }
        tokmeta[b * TPB_TOK + t] = m1 | (m2 << 6) | (r1 << 12) | (r2 << 17);
    }
}

// ---------------------------------------------------------------------------
// Row writer: stream one 8192-float row (base float-index == 1 mod 4) as
// zeros with up to two nonzeros placed inline.  base+3 is 16B-aligned.
//   head floats base[0..2] + tail base[8191] by thread 255 (idle in chunk 7).
//   chunks: float4 at base+3+4k, k in [0,2047), k = j*256+tid.
// p == -1 means "no nonzero" (rel >= 0 never matches).
// ---------------------------------------------------------------------------
__device__ __forceinline__ void write_row(
    float* __restrict__ base, int p1, float v1, int p2, float v2, int tid)
{
    if (tid == 255) {
        base[0]    = (p1 == 0)    ? v1 : ((p2 == 0)    ? v2 : 0.f);
        base[1]    = (p1 == 1)    ? v1 : ((p2 == 1)    ? v2 : 0.f);
        base[2]    = (p1 == 2)    ? v1 : ((p2 == 2)    ? v2 : 0.f);
        base[8191] = (p1 == 8191) ? v1 : ((p2 == 8191) ? v2 : 0.f);
    }
    float* cbase = base + 3;           // 16B-aligned
    #pragma unroll
    for (int j = 0; j < 8; ++j) {
        const int k = j * 256 + tid;
        if (j < 7 || k < 2047) {
            const int rel = 4 * k + 3; // float index within row of component x
            float4 z;
            z.x = (rel + 0 == p1) ? v1 : ((rel + 0 == p2) ? v2 : 0.f);
            z.y = (rel + 1 == p1) ? v1 : ((rel + 1 == p2) ? v2 : 0.f);
            z.z = (rel + 2 == p1) ? v1 : ((rel + 2 == p2) ? v2 : 0.f);
            z.w = (rel + 3 == p1) ? v1 : ((rel + 3 == p2) ? v2 : 0.f);
            *(float4*)(cbase + 4 * (long)k) = z;
        }
    }
}

// ---------------------------------------------------------------------------
// K2: redundant per-block prefix scan (bc arrays L2-resident) + direct
// full-row writes for this block's 4 tokens (combine + mask, 256 KB/block).
// No fill/scatter ordering: each row is fully owned by one block.
// 1024 blocks x 256 threads; block 0 also writes l_aux (out[0]).
// ---------------------------------------------------------------------------
__global__ __launch_bounds__(256) void k2_write(
    const int*   __restrict__ bc1,
    const int*   __restrict__ bc2,
    const float* __restrict__ pg,
    const int*   __restrict__ tokmeta,
    const float2* __restrict__ tokg,
    float* __restrict__ out)
{
    const int tid = threadIdx.x;
    const int b   = blockIdx.x;        // [0, 1024)
    const int gb  = b >> 2;            // gate block owning tokens [4b, 4b+4)

    __shared__ int   s_off1[64], s_off2[64], s_cnt1[64];
    __shared__ float s_gs[64];
    __shared__ int   s_p1[TPW], s_p2[TPW];
    __shared__ float s_v1[TPW], s_v2[TPW];

    if (tid < 64) {
        // exclusive prefix of bc1 over blocks, capture own offset + total
        int o1 = 0, mine = 0;
        #pragma unroll 8
        for (int blk = 0; blk < NGATE; ++blk) {
            if (blk == gb) mine = o1;
            o1 += bc1[blk * 64 + tid];
        }
        s_off1[tid] = mine;
        s_cnt1[tid] = o1;
    } else if (tid < 128) {
        const int e = tid - 64;
        int o2 = 0, mine = 0;
        #pragma unroll 8
        for (int blk = 0; blk < NGATE; ++blk) {
            if (blk == gb) mine = o2;
            o2 += bc2[blk * 64 + e];
        }
        s_off2[e] = mine;
    } else if (tid < 192 && b == 0) {
        const int e = tid - 128;
        float gs = 0.f;
        #pragma unroll 8
        for (int blk = 0; blk < NGATE; ++blk) gs += pg[blk * 64 + e];
        s_gs[e] = gs;
    }
    __syncthreads();

    if (tid < TPW) {
        const int s = b * TPW + tid;
        const int m = tokmeta[s];
        const int i1  =  m        & 63;
        const int i2  = (m >> 6)  & 63;
        const int lr1 = (m >> 12) & 31;
        const int lr2 = (m >> 17) & 31;
        const float2 g = tokg[s];
        const int loc1 = lr1 + s_off1[i1];
        const int loc2 = lr2 + s_off2[i2] + s_cnt1[i2];
        float g1 = g.x, g2 = g.y;
        const bool k1 = loc1 < CAPC, k2 = loc2 < CAPC;
        g1 = k1 ? g1 : 0.f;
        g2 = k2 ? g2 : 0.f;
        const float denom = fmaxf(g1 + g2, 1.1920929e-07f);  // finfo(f32).eps
        g1 /= denom;
        g2 /= denom;
        s_p1[tid] = (k1 && g1 != 0.f) ? (i1 * CAPC + loc1) : -1;
        s_v1[tid] = g1;
        s_p2[tid] = (k2 && g2 != 0.f) ? (i2 * CAPC + loc2) : -1;
        s_v2[tid] = g2;
    } else if (tid == 192 && b == 0) {
        // l_aux = (E / S^2) * sum_e gs_e * cnt1_e
        float prod = 0.f;
        #pragma unroll 8
        for (int e = 0; e < 64; ++e) prod += s_gs[e] * (float)s_cnt1[e];
        out[0] = prod * (float)EE / ((float)SS * (float)SS);
    }
    __syncthreads();

    // stream 4 tokens x {combine, mask} rows (zeros + inline nonzeros)
    for (int t = 0; t < TPW; ++t) {
        const int s = b * TPW + t;
        const int p1 = s_p1[t], p2 = s_p2[t];
        const float v1 = s_v1[t], v2 = s_v2[t];
        float* combine = out + 1 + (long)s * ROW;
        float* mask    = out + 1 + SEC + (long)s * ROW;
        write_row(combine, p1, v1, p2, v2, tid);
        write_row(mask,    p1, 1.f, p2, 1.f, tid);
    }
}

// ---------------------------------------------------------------------------
// Launch: gate -> scan+direct-write.  Plain sequential dispatches (the
// cooperative launch paid ~+84us/iter under graph replay — reverted).
// ---------------------------------------------------------------------------
extern "C" void kernel_launch(void* const* d_in, const int* in_sizes, int n_in,
                              void* d_out, int out_size, void* d_ws, size_t ws_size,
                              hipStream_t stream) {
    const float* logits = (const float*)d_in[0];
    const float* noise  = (const float*)d_in[1];
    float* out = (float*)d_out;

    char* ws = (char*)d_ws;
    int*    bc1     = (int*)   (ws + 0);        // 64 KB
    int*    bc2     = (int*)   (ws + 65536);    // 64 KB
    float*  pg      = (float*) (ws + 131072);   // 64 KB
    int*    tokmeta = (int*)   (ws + 196608);   // 16 KB
    float2* tokg    = (float2*)(ws + 212992);   // 32 KB

    k1_gate<<<NGATE, 256, 0, stream>>>(logits, noise, bc1, bc2, pg, tokmeta, tokg);
    k2_write<<<NW, 256, 0, stream>>>(bc1, bc2, pg, tokmeta, tokg, out);
}